// Round 9
// baseline (38.578 us; speedup 1.0000x reference)
//
#include <hip/hip_runtime.h>

#define POOL 7
#define NUM_ROIS 512
#define H_IMG 128
#define W_IMG 128
#define C_IMG 1024
#define NITEMS (NUM_ROIS * POOL)   // 3584 work items = (roi, py) rows
#define NBINS 8192                 // key = ay0*64 + roi.x  (row, col-origin)

typedef float f32x4 __attribute__((ext_vector_type(4)));

// ---------------------------------------------------------------------------
// Pre-pass: counting-sort the 3584 (roi,py) items by (source row ay0, roi x).
// Finer key than r4-r8's row-only sort: items sharing a row AND column range
// become temporally adjacent, shrinking read reuse distance from ~6.3MB to
// <1MB so image lines survive in the 4MB per-XCD L2 (they were marginally
// evicted before reuse, forcing ~400MB/call onto the slower L3 path).
// 1 block, 1024 threads, 8192-bin hist + hierarchical shuffle scan in LDS.
// Within-bin order is atomic-timing dependent but harmless.
// ---------------------------------------------------------------------------
__device__ __forceinline__ int item_key(const int4 roi, int py) {
    const float hf = (float)roi.w;                       // h
    float ysf = ((float)py + 0.5f) * hf / 7.0f - 0.5f;
    ysf = fminf(fmaxf(ysf, 0.0f), hf - 1.0f);
    const int ay0 = roi.y + (int)floorf(ysf);            // [0,127]
    return (ay0 << 6) + roi.x;                           // x in [0,64)
}

__global__ __launch_bounds__(1024) void build_perm_kernel(
    const int* __restrict__ rois, int* __restrict__ perm)
{
    __shared__ int hist[NBINS];      // 32 KB
    __shared__ int wtot[16];
    __shared__ int wbase[16];
    const int tid  = threadIdx.x;
    const int lane = tid & 63;
    const int wid  = tid >> 6;

    #pragma unroll
    for (int i = tid; i < NBINS; i += 1024) hist[i] = 0;
    __syncthreads();

    for (int i = tid; i < NITEMS; i += 1024) {
        const int r = i / POOL, py = i - r * POOL;
        const int4 roi = ((const int4*)rois)[r];
        atomicAdd(&hist[item_key(roi, py)], 1);
    }
    __syncthreads();

    // Exclusive scan of 8192 bins: thread owns 8 consecutive bins.
    int loc[8];
    int s = 0;
    #pragma unroll
    for (int j = 0; j < 8; ++j) {
        loc[j] = s;
        s += hist[8 * tid + j];
    }
    // wave-inclusive scan of per-thread totals
    int inc = s;
    #pragma unroll
    for (int off = 1; off < 64; off <<= 1) {
        const int u = __shfl_up(inc, off, 64);
        if (lane >= off) inc += u;
    }
    if (lane == 63) wtot[wid] = inc;
    __syncthreads();
    if (wid == 0 && lane < 16) {
        int v = wtot[lane];
        int winc = v;
        #pragma unroll
        for (int off = 1; off < 16; off <<= 1) {
            const int u = __shfl_up(winc, off, 16);
            if (lane >= off) winc += u;
        }
        wbase[lane] = winc - v;      // exclusive wave offset
    }
    __syncthreads();
    const int texcl = wbase[wid] + inc - s;   // exclusive offset of this thread
    #pragma unroll
    for (int j = 0; j < 8; ++j)
        hist[8 * tid + j] = texcl + loc[j];   // scatter cursors
    __syncthreads();

    for (int i = tid; i < NITEMS; i += 1024) {
        const int r = i / POOL, py = i - r * POOL;
        const int4 roi = ((const int4*)rois)[r];
        const int pos = atomicAdd(&hist[item_key(roi, py)], 1);
        perm[pos] = i;
    }
}

// ---------------------------------------------------------------------------
// Main kernel: one 256-thread block per (roi, py) output row, work order
// from perm ((row,x)-sorted; each XCD gets a contiguous slice). NT stores
// keep the 100MB write stream from evicting the L2 read window.
// ---------------------------------------------------------------------------
__global__ __launch_bounds__(256) void roi_pool_row_kernel(
    const float* __restrict__ img,   // (H, W, C)
    const int*   __restrict__ rois,  // (R, 4) as (x, y, w, h)
    const int*   __restrict__ perm,  // (NITEMS) sorted work ids
    float*       __restrict__ out)   // (R, P, P, C)
{
    const int bid  = blockIdx.x;
    const int swz  = (bid & 7) * (NITEMS / 8) + (bid >> 3);
    const int item = perm[swz];
    const int r    = item / POOL;
    const int py   = item - r * POOL;

    const int4 roi = ((const int4*)rois)[r];
    const int x = roi.x, y = roi.y, w = roi.z, h = roi.w;
    const float hf = (float)h, wf = (float)w;

    // y interpolation (same fp32 expression order as reference)
    float ysf = ((float)py + 0.5f) * hf / 7.0f - 0.5f;
    ysf = fminf(fmaxf(ysf, 0.0f), hf - 1.0f);
    const int   y0 = (int)floorf(ysf);
    const int   y1 = min(y0 + 1, h - 1);
    const float fy = ysf - (float)y0;
    const float gy = 1.0f - fy;

    const f32x4* __restrict__ row0 =
        (const f32x4*)(img + (size_t)(y + y0) * W_IMG * C_IMG);
    const f32x4* __restrict__ row1 =
        (const f32x4*)(img + (size_t)(y + y1) * W_IMG * C_IMG);

    // x interpolation for all 7 px
    int   ax0[POOL], ax1[POOL];
    float fx[POOL];
    #pragma unroll
    for (int px = 0; px < POOL; ++px) {
        float xsf = ((float)px + 0.5f) * wf / 7.0f - 0.5f;
        xsf = fminf(fmaxf(xsf, 0.0f), wf - 1.0f);
        const int x0 = (int)floorf(xsf);
        const int x1 = min(x0 + 1, w - 1);
        fx[px]  = xsf - (float)x0;
        ax0[px] = x + x0;
        ax1[px] = x + x1;
    }

    const int t = threadIdx.x;   // 0..255 ; C/4 == 256 exactly

    f32x4 A[POOL], B[POOL], C_[POOL], D[POOL];
    #pragma unroll
    for (int px = 0; px < POOL; ++px) {
        A[px]  = row0[(ax0[px] << 8) + t];
        B[px]  = row0[(ax1[px] << 8) + t];
    }
    #pragma unroll
    for (int px = 0; px < POOL; ++px) {
        C_[px] = row1[(ax0[px] << 8) + t];
        D[px]  = row1[(ax1[px] << 8) + t];
    }

    f32x4* __restrict__ po =
        (f32x4*)(out + ((size_t)(r * 49 + py * 7)) * C_IMG);

    #pragma unroll
    for (int px = 0; px < POOL; ++px) {
        const float f = fx[px], g = 1.0f - f;
        f32x4 top = A[px]  * g + B[px] * f;
        f32x4 bot = C_[px] * g + D[px] * f;
        f32x4 o   = top * gy + bot * fy;
        __builtin_nontemporal_store(o, &po[(px << 8) + t]);
    }
}

extern "C" void kernel_launch(void* const* d_in, const int* in_sizes, int n_in,
                              void* d_out, int out_size, void* d_ws, size_t ws_size,
                              hipStream_t stream) {
    const float* img  = (const float*)d_in[0];   // (1,128,128,1024) fp32
    const int*   rois = (const int*)d_in[1];     // (1,512,4) int32
    float*       out  = (float*)d_out;           // (1,512,7,7,1024) fp32
    int*         perm = (int*)d_ws;              // NITEMS ints of scratch

    build_perm_kernel<<<1, 1024, 0, stream>>>(rois, perm);
    roi_pool_row_kernel<<<NITEMS, 256, 0, stream>>>(img, rois, perm, out);
}